// Round 1
// baseline (134.695 us; speedup 1.0000x reference)
//
#include <hip/hip_runtime.h>

// =============================================================================
// QuantumContrastiveModel — mathematical reduction:
//   StronglyEntanglingLayers is a fixed 16x16 UNITARY applied to BOTH states;
//   fidelity |<U va|U vb>|^2 = (va.vb)^2 — the circuit cancels, theta unused.
//   With u = tanh(relu(x@W1+b1)@W2+b2):
//     fid = clip( (ua.ub)^2 / (max(|ua|,1e-8)*max(|ub|,1e-8))^2, 0, 1 )
//   R1: 170us latency-bound. R2: depth-1 prefetch pipeline -> 117us.
//   R3: occupancy was hard-capped at 16 waves/CU (65536/16 pairs-per-wave waves)
//       and ~80 live regs. Pack 8 a-rows + 8 b-rows into ONE 16x16 A-fragment:
//       one MFMA computes both dot products -> 8 pairs/wave, 8192 waves,
//       32 waves/CU, acc halves to 16 regs, loop fits <=64 regs (256,8 bound).
// =============================================================================

#define KDIM   784
#define HDIM   64
#define KSTEPS 25                        // ceil(784/32); last step zero-padded
#define W1S_ELEMS (KSTEPS * 4 * 64 * 8)  // 51200 bf16 in B-fragment order
#define W1S_BYTES (W1S_ELEMS * 2)        // 102400 bytes

typedef float  f32x4  __attribute__((ext_vector_type(4)));
typedef short  bf16x8 __attribute__((ext_vector_type(8)));

__device__ __forceinline__ unsigned short f2bf(float f) {
  unsigned u = __float_as_uint(f);
  u += 0x7fffu + ((u >> 16) & 1u);       // round-to-nearest-even
  return (unsigned short)(u >> 16);
}

__device__ __forceinline__ float bf2f(unsigned short h) {
  return __uint_as_float(((unsigned)h) << 16);
}

__device__ __forceinline__ bf16x8 cvt8(f32x4 lo, f32x4 hi) {
  bf16x8 r;
  r[0] = (short)f2bf(lo[0]); r[1] = (short)f2bf(lo[1]);
  r[2] = (short)f2bf(lo[2]); r[3] = (short)f2bf(lo[3]);
  r[4] = (short)f2bf(hi[0]); r[5] = (short)f2bf(hi[1]);
  r[6] = (short)f2bf(hi[2]); r[7] = (short)f2bf(hi[3]);
  return r;
}

__device__ __forceinline__ float tanh_fast(float x) {
  float e = __expf(2.0f * x);
  return 1.0f - 2.0f / (e + 1.0f);       // exact limits at +-inf
}

// --- prep: W1 (784x64 f32) -> bf16 in MFMA B-fragment order, K padded to 800;
//           W2 (64x16) -> transposed (16x64) f32.  (unchanged, verified)
__global__ __launch_bounds__(256)
void prep_kernel(const float* __restrict__ W1, const float* __restrict__ W2,
                 unsigned short* __restrict__ w1s, float* __restrict__ w2t) {
  int tid = blockIdx.x * 256 + threadIdx.x;
  if (tid < W1S_ELEMS) {
    int j  = tid & 7;            // element within 8-wide fragment
    int l  = (tid >> 3) & 63;    // lane
    int st = tid >> 9;           // s*4 + t
    int s  = st >> 2;
    int t  = st & 3;
    int k  = s * 32 + (l >> 4) * 8 + j;   // B[k][n]: k = quad*8+j
    int n  = t * 16 + (l & 15);           //          n = lane&15
    float v = (k < KDIM) ? W1[k * HDIM + n] : 0.0f;
    w1s[tid] = f2bf(v);
  }
  if (tid < HDIM * 16) {
    int c = tid >> 6;            // 0..15
    int k = tid & 63;            // 0..63
    w2t[c * HDIM + k] = W2[k * 16 + c];
  }
}

// --- main: 32 pairs/block, 4 waves, 8 pairs/wave.
//     A-fragment rows 0-7 = a-rows, rows 8-15 = b-rows -> ONE mfma does both.
//     Depth-1 software pipeline: A-loads for s+1 in flight while computing s.
__global__ __launch_bounds__(256, 8)
void qcm_kernel(const float* __restrict__ img_a, const float* __restrict__ img_b,
                const float* __restrict__ b1,    const float* __restrict__ b2,
                const unsigned short* __restrict__ w1s,
                const float* __restrict__ w2t,
                float* __restrict__ out) {
  __shared__ __attribute__((aligned(16))) unsigned short lds_h[64][72]; // 9.2KB

  const int tid  = threadIdx.x;
  const int wave = tid >> 6;
  const int lane = tid & 63;
  const int m    = lane & 15;     // A-frag row: 0-7 -> a pair m, 8-15 -> b pair m-8
  const int quad = lane >> 4;
  const int p0   = blockIdx.x * 32 + wave * 8;

  const float* row = (m < 8)
      ? (img_a + (size_t)(p0 + m)     * KDIM)
      : (img_b + (size_t)(p0 + m - 8) * KDIM);
  const int koff = quad * 8;      // A-frag k-offset: k = quad*8 + j

  f32x4 acc[4];
  #pragma unroll
  for (int t = 0; t < 4; ++t)
    acc[t][0] = acc[t][1] = acc[t][2] = acc[t][3] = 0.0f;

  const int4* bwl = (const int4*)w1s + lane;
  f32x4 z4; z4[0] = z4[1] = z4[2] = z4[3] = 0.0f;

  // prologue: load s=0
  f32x4 c0 = *(const f32x4*)(row + koff);
  f32x4 c1 = *(const f32x4*)(row + koff + 4);

  for (int s = 0; s < KSTEPS; ++s) {
    // B frags for s — issue first; cvt VALU below covers part of their L2 latency
    int4 w0 = bwl[s * 256];
    int4 w1 = bwl[s * 256 + 64];
    int4 w2 = bwl[s * 256 + 128];
    int4 w3 = bwl[s * 256 + 192];

    // prefetch A for s+1 (depth-1 pipeline)
    f32x4 n0 = z4, n1 = z4;
    if (s < 23) {
      const int kb = (s + 1) * 32 + koff;
      n0 = *(const f32x4*)(row + kb);
      n1 = *(const f32x4*)(row + kb + 4);
    } else if (s == 23) {
      // tail step: k = 768..799, quads 2,3 past 784 -> stay zero (w1s 0 too)
      if (quad < 2) {
        n0 = *(const f32x4*)(row + 768 + koff);
        n1 = *(const f32x4*)(row + 768 + koff + 4);
      }
    }

    bf16x8 fa = cvt8(c0, c1);

    acc[0] = __builtin_amdgcn_mfma_f32_16x16x32_bf16(
        fa, __builtin_bit_cast(bf16x8, w0), acc[0], 0, 0, 0);
    acc[1] = __builtin_amdgcn_mfma_f32_16x16x32_bf16(
        fa, __builtin_bit_cast(bf16x8, w1), acc[1], 0, 0, 0);
    acc[2] = __builtin_amdgcn_mfma_f32_16x16x32_bf16(
        fa, __builtin_bit_cast(bf16x8, w2), acc[2], 0, 0, 0);
    acc[3] = __builtin_amdgcn_mfma_f32_16x16x32_bf16(
        fa, __builtin_bit_cast(bf16x8, w3), acc[3], 0, 0, 0);

    c0 = n0; c1 = n1;
  }

  // epilogue: bias + relu, park h in LDS as bf16.
  // C-frag: row = quad*4+j (0-7 = a-pairs, 8-15 = b-pairs), col = t*16 + m.
  #pragma unroll
  for (int t = 0; t < 4; ++t) {
    float bias = b1[t * 16 + m];
    #pragma unroll
    for (int j = 0; j < 4; ++j) {
      float h = fmaxf(acc[t][j] + bias, 0.0f);
      lds_h[wave * 16 + quad * 4 + j][t * 16 + m] = f2bf(h);
    }
  }
  __syncthreads();

  // phase 2: 8 threads per pair; each computes 2 of the 16 z-columns for a and b
  const int p = tid >> 3;            // 0..31 local pair
  const int q = tid & 7;             // 0..7 -> cols q*2, q*2+1
  const int wsrc = p >> 3;
  const int r = p & 7;
  const unsigned short* ha_row = &lds_h[wsrc * 16 + r][0];
  const unsigned short* hb_row = &lds_h[wsrc * 16 + 8 + r][0];

  float za[2], zb[2];
  za[0] = b2[q * 2];     zb[0] = za[0];
  za[1] = b2[q * 2 + 1]; zb[1] = za[1];

  for (int k = 0; k < HDIM; k += 4) {
    uint2 ua = *(const uint2*)(ha_row + k);
    uint2 ub = *(const uint2*)(hb_row + k);
    float a0 = bf2f((unsigned short)(ua.x & 0xffff));
    float a1 = bf2f((unsigned short)(ua.x >> 16));
    float a2 = bf2f((unsigned short)(ua.y & 0xffff));
    float a3 = bf2f((unsigned short)(ua.y >> 16));
    float b0v = bf2f((unsigned short)(ub.x & 0xffff));
    float b1v = bf2f((unsigned short)(ub.x >> 16));
    float b2v = bf2f((unsigned short)(ub.y & 0xffff));
    float b3v = bf2f((unsigned short)(ub.y >> 16));
    #pragma unroll
    for (int i = 0; i < 2; ++i) {
      f32x4 wv = *(const f32x4*)(w2t + (q * 2 + i) * HDIM + k);
      za[i] += a0 * wv[0] + a1 * wv[1] + a2 * wv[2] + a3 * wv[3];
      zb[i] += b0v * wv[0] + b1v * wv[1] + b2v * wv[2] + b3v * wv[3];
    }
  }

  float d = 0.0f, na2 = 0.0f, nb2 = 0.0f;
  #pragma unroll
  for (int i = 0; i < 2; ++i) {
    float ua = tanh_fast(za[i]);
    float ub = tanh_fast(zb[i]);
    d   += ua * ub;
    na2 += ua * ua;
    nb2 += ub * ub;
  }
  d   += __shfl_xor(d, 1);   d   += __shfl_xor(d, 2);   d   += __shfl_xor(d, 4);
  na2 += __shfl_xor(na2, 1); na2 += __shfl_xor(na2, 2); na2 += __shfl_xor(na2, 4);
  nb2 += __shfl_xor(nb2, 1); nb2 += __shfl_xor(nb2, 2); nb2 += __shfl_xor(nb2, 4);

  if (q == 0) {
    float den = fmaxf(sqrtf(na2), 1e-8f) * fmaxf(sqrtf(nb2), 1e-8f);
    float ov  = d / den;
    float fid = ov * ov;
    out[blockIdx.x * 32 + p] = fminf(fid, 1.0f);
  }
}

extern "C" void kernel_launch(void* const* d_in, const int* in_sizes, int n_in,
                              void* d_out, int out_size, void* d_ws, size_t ws_size,
                              hipStream_t stream) {
  const float* img_a = (const float*)d_in[0];
  const float* img_b = (const float*)d_in[1];
  const float* W1    = (const float*)d_in[2];
  const float* b1    = (const float*)d_in[3];
  const float* W2    = (const float*)d_in[4];
  const float* b2    = (const float*)d_in[5];
  // d_in[6] = theta: unused — the circuit is unitary, fidelity is invariant.

  unsigned short* w1s = (unsigned short*)d_ws;
  float* w2t = (float*)((char*)d_ws + W1S_BYTES);

  prep_kernel<<<(W1S_ELEMS + 255) / 256, 256, 0, stream>>>(W1, W2, w1s, w2t);

  const int n_pairs = out_size;              // 65536
  qcm_kernel<<<n_pairs / 32, 256, 0, stream>>>(img_a, img_b, b1, b2, w1s, w2t,
                                               (float*)d_out);
}

// Round 2
// 117.875 us; speedup vs baseline: 1.1427x; 1.1427x over previous
//
#include <hip/hip_runtime.h>

// =============================================================================
// QuantumContrastiveModel — mathematical reduction:
//   StronglyEntanglingLayers is a fixed 16x16 UNITARY applied to BOTH states;
//   fidelity |<U va|U vb>|^2 = (va.vb)^2 — the circuit cancels, theta unused.
//   With u = tanh(relu(x@W1+b1)@W2+b2):
//     fid = clip( (ua.ub)^2 / (max(|ua|,1e-8)*max(|ub|,1e-8))^2, 0, 1 )
//   R1: 170us latency-bound. R2: depth-1 prefetch -> 117us.
//   R3 (FAILED, 135us): 8 pairs/wave doubled occupancy 38->67% with ZERO
//       profiled speedup -> NOT latency-bound; per-CU VMEM request path is
//       the limiter, and halving pairs/wave doubled W line-requests/pair.
//   R4: revert to 16 pairs/wave; stage ALL of w1s (100KB) in LDS once per
//       block. 1024-thr blocks (256 pairs) -> grid=256 = 1 block/CU, each CU
//       stages W exactly once; K-loop reads W via ds_read_b128 (lgkm path,
//       no TA pressure), A-loads are the only VMEM. LDS reused as h-buffer
//       for phase 2 after the loop. Per-CU line-requests: ~77K -> ~27K.
// =============================================================================

#define KDIM   784
#define HDIM   64
#define KSTEPS 25                        // ceil(784/32); last step zero-padded
#define W1S_ELEMS (KSTEPS * 4 * 64 * 8)  // 51200 bf16 in B-fragment order
#define W1S_BYTES (W1S_ELEMS * 2)        // 102400 bytes
#define W1S_INT4  (W1S_BYTES / 16)       // 6400 int4

typedef float  f32x4  __attribute__((ext_vector_type(4)));
typedef short  bf16x8 __attribute__((ext_vector_type(8)));

__device__ __forceinline__ unsigned short f2bf(float f) {
  unsigned u = __float_as_uint(f);
  u += 0x7fffu + ((u >> 16) & 1u);       // round-to-nearest-even
  return (unsigned short)(u >> 16);
}

__device__ __forceinline__ float bf2f(unsigned short h) {
  return __uint_as_float(((unsigned)h) << 16);
}

__device__ __forceinline__ bf16x8 cvt8(f32x4 lo, f32x4 hi) {
  bf16x8 r;
  r[0] = (short)f2bf(lo[0]); r[1] = (short)f2bf(lo[1]);
  r[2] = (short)f2bf(lo[2]); r[3] = (short)f2bf(lo[3]);
  r[4] = (short)f2bf(hi[0]); r[5] = (short)f2bf(hi[1]);
  r[6] = (short)f2bf(hi[2]); r[7] = (short)f2bf(hi[3]);
  return r;
}

__device__ __forceinline__ float tanh_fast(float x) {
  float e = __expf(2.0f * x);
  return 1.0f - 2.0f / (e + 1.0f);       // exact limits at +-inf
}

// A-loads for K-step st: k-range [st*32+koff, st*32+koff+8) for rows a,b.
// st==24 is the zero-padded tail (only quads 0,1 in range); st>24 -> zeros.
__device__ __forceinline__ void load_a(const float* __restrict__ rowA,
                                       const float* __restrict__ rowB,
                                       int st, int koff, int quad,
                                       f32x4& r0, f32x4& r1,
                                       f32x4& r2, f32x4& r3) {
  f32x4 z; z[0] = z[1] = z[2] = z[3] = 0.0f;
  r0 = r1 = r2 = r3 = z;
  if (st < 24) {
    const int kb = st * 32 + koff;
    r0 = *(const f32x4*)(rowA + kb);
    r1 = *(const f32x4*)(rowA + kb + 4);
    r2 = *(const f32x4*)(rowB + kb);
    r3 = *(const f32x4*)(rowB + kb + 4);
  } else if (st == 24) {
    if (quad < 2) {                      // k = 768..783 valid, 784..799 padded
      const int kb = 768 + koff;
      r0 = *(const f32x4*)(rowA + kb);
      r1 = *(const f32x4*)(rowA + kb + 4);
      r2 = *(const f32x4*)(rowB + kb);
      r3 = *(const f32x4*)(rowB + kb + 4);
    }
  }
}

// --- prep: W1 (784x64 f32) -> bf16 in MFMA B-fragment order, K padded to 800;
//           W2 (64x16) -> transposed (16x64) f32.  (unchanged, verified)
__global__ __launch_bounds__(256)
void prep_kernel(const float* __restrict__ W1, const float* __restrict__ W2,
                 unsigned short* __restrict__ w1s, float* __restrict__ w2t) {
  int tid = blockIdx.x * 256 + threadIdx.x;
  if (tid < W1S_ELEMS) {
    int j  = tid & 7;            // element within 8-wide fragment
    int l  = (tid >> 3) & 63;    // lane
    int st = tid >> 9;           // s*4 + t
    int s  = st >> 2;
    int t  = st & 3;
    int k  = s * 32 + (l >> 4) * 8 + j;   // B[k][n]: k = quad*8+j
    int n  = t * 16 + (l & 15);           //          n = lane&15
    float v = (k < KDIM) ? W1[k * HDIM + n] : 0.0f;
    w1s[tid] = f2bf(v);
  }
  if (tid < HDIM * 16) {
    int c = tid >> 6;            // 0..15
    int k = tid & 63;            // 0..63
    w2t[c * HDIM + k] = W2[k * 16 + c];
  }
}

// --- main: 1024 threads = 16 waves = 256 pairs/block; grid = 256 (1 block/CU).
//     W1 fully staged in LDS once; K-loop VMEM = A-loads only (depth-2 eff.).
__global__ __launch_bounds__(1024, 4)
void qcm_kernel(const float* __restrict__ img_a, const float* __restrict__ img_b,
                const float* __restrict__ b1,    const float* __restrict__ b2,
                const unsigned short* __restrict__ w1s,
                const float* __restrict__ w2t,
                float* __restrict__ out) {
  // 100KB: W1 fragments during the K-loop, then REUSED as h-buffer [512][72].
  __shared__ __attribute__((aligned(16))) char smem[W1S_BYTES];

  const int tid = threadIdx.x;

  // --- one-shot stage of w1s into LDS (coalesced int4 copy) ---
  {
    const int4* src = (const int4*)w1s;
    int4* dst = (int4*)smem;
    #pragma unroll
    for (int i = 0; i < 7; ++i) {
      int idx = tid + i * 1024;
      if (idx < W1S_INT4) dst[idx] = src[idx];
    }
  }
  __syncthreads();

  const int wave = tid >> 6;      // 0..15
  const int lane = tid & 63;
  const int m    = lane & 15;     // A-frag row / C-frag col
  const int quad = lane >> 4;
  const int p0   = blockIdx.x * 256 + wave * 16;

  const float* rowA = img_a + (size_t)(p0 + m) * KDIM;
  const float* rowB = img_b + (size_t)(p0 + m) * KDIM;
  const int koff = quad * 8;      // A-frag k-offset: k = quad*8 + j

  f32x4 accA[4], accB[4];
  #pragma unroll
  for (int t = 0; t < 4; ++t) {
    accA[t][0] = accA[t][1] = accA[t][2] = accA[t][3] = 0.0f;
    accB[t][0] = accB[t][1] = accB[t][2] = accB[t][3] = 0.0f;
  }

  const int4* wl = (const int4*)smem;   // W fragments, lane-contiguous b128

  // --- pipeline prologue: data for s=0 (converted) and s=1 (raw f32) ---
  f32x4 t0, t1, t2, t3;
  load_a(rowA, rowB, 0, koff, quad, t0, t1, t2, t3);
  f32x4 pa0, pa1, pb0, pb1;
  load_a(rowA, rowB, 1, koff, quad, pa0, pa1, pb0, pb1);
  bf16x8 curA = cvt8(t0, t1);
  bf16x8 curB = cvt8(t2, t3);

  for (int s = 0; s < KSTEPS; ++s) {
    // issue A-loads for s+2 first (depth-2; zeros past the tail)
    f32x4 f0, f1, f2, f3;
    load_a(rowA, rowB, s + 2, koff, quad, f0, f1, f2, f3);

    // W fragments from LDS (ds_read_b128, lane*16 contiguous — m97 pattern)
    const int base = s * 256 + lane;
    int4 w0 = wl[base];
    int4 w1 = wl[base + 64];
    int4 w2 = wl[base + 128];
    int4 w3 = wl[base + 192];

    accA[0] = __builtin_amdgcn_mfma_f32_16x16x32_bf16(
        curA, __builtin_bit_cast(bf16x8, w0), accA[0], 0, 0, 0);
    accB[0] = __builtin_amdgcn_mfma_f32_16x16x32_bf16(
        curB, __builtin_bit_cast(bf16x8, w0), accB[0], 0, 0, 0);
    accA[1] = __builtin_amdgcn_mfma_f32_16x16x32_bf16(
        curA, __builtin_bit_cast(bf16x8, w1), accA[1], 0, 0, 0);
    accB[1] = __builtin_amdgcn_mfma_f32_16x16x32_bf16(
        curB, __builtin_bit_cast(bf16x8, w1), accB[1], 0, 0, 0);
    accA[2] = __builtin_amdgcn_mfma_f32_16x16x32_bf16(
        curA, __builtin_bit_cast(bf16x8, w2), accA[2], 0, 0, 0);
    accB[2] = __builtin_amdgcn_mfma_f32_16x16x32_bf16(
        curB, __builtin_bit_cast(bf16x8, w2), accB[2], 0, 0, 0);
    accA[3] = __builtin_amdgcn_mfma_f32_16x16x32_bf16(
        curA, __builtin_bit_cast(bf16x8, w3), accA[3], 0, 0, 0);
    accB[3] = __builtin_amdgcn_mfma_f32_16x16x32_bf16(
        curB, __builtin_bit_cast(bf16x8, w3), accB[3], 0, 0, 0);

    // convert data for s+1 (loaded one iter ago — full-iter latency slack)
    curA = cvt8(pa0, pa1);
    curB = cvt8(pb0, pb1);
    pa0 = f0; pa1 = f1; pb0 = f2; pb1 = f3;
  }

  // all W reads done before smem is repurposed as the h-buffer
  __syncthreads();
  unsigned short (*lds_h)[72] = (unsigned short(*)[72])smem;  // 512x72 = 73.7KB

  // epilogue: bias + relu, park h as bf16 (C-frag: row=quad*4+j, col=t*16+m)
  #pragma unroll
  for (int t = 0; t < 4; ++t) {
    float bias = b1[t * 16 + m];
    const int ra = wave * 32;
    #pragma unroll
    for (int j = 0; j < 4; ++j) {
      float ha = fmaxf(accA[t][j] + bias, 0.0f);
      float hb = fmaxf(accB[t][j] + bias, 0.0f);
      lds_h[ra +      quad * 4 + j][t * 16 + m] = f2bf(ha);
      lds_h[ra + 16 + quad * 4 + j][t * 16 + m] = f2bf(hb);
    }
  }
  __syncthreads();

  // phase 2: 4 threads per pair; each computes 4 of the 16 z-columns for a,b
  const int p = tid >> 2;            // 0..255 local pair
  const int q = tid & 3;
  const int wsrc = p >> 4;
  const int r = p & 15;
  const unsigned short* ha_row = &lds_h[wsrc * 32 + r][0];
  const unsigned short* hb_row = &lds_h[wsrc * 32 + 16 + r][0];

  float za[4], zb[4];
  #pragma unroll
  for (int i = 0; i < 4; ++i) { za[i] = b2[q * 4 + i]; zb[i] = za[i]; }

  for (int k = 0; k < HDIM; k += 4) {
    uint2 ua = *(const uint2*)(ha_row + k);
    uint2 ub = *(const uint2*)(hb_row + k);
    float a0 = bf2f((unsigned short)(ua.x & 0xffff));
    float a1 = bf2f((unsigned short)(ua.x >> 16));
    float a2 = bf2f((unsigned short)(ua.y & 0xffff));
    float a3 = bf2f((unsigned short)(ua.y >> 16));
    float b0v = bf2f((unsigned short)(ub.x & 0xffff));
    float b1v = bf2f((unsigned short)(ub.x >> 16));
    float b2v = bf2f((unsigned short)(ub.y & 0xffff));
    float b3v = bf2f((unsigned short)(ub.y >> 16));
    #pragma unroll
    for (int i = 0; i < 4; ++i) {
      f32x4 wv = *(const f32x4*)(w2t + (q * 4 + i) * HDIM + k);
      za[i] += a0 * wv[0] + a1 * wv[1] + a2 * wv[2] + a3 * wv[3];
      zb[i] += b0v * wv[0] + b1v * wv[1] + b2v * wv[2] + b3v * wv[3];
    }
  }

  float d = 0.0f, na2 = 0.0f, nb2 = 0.0f;
  #pragma unroll
  for (int i = 0; i < 4; ++i) {
    float ua = tanh_fast(za[i]);
    float ub = tanh_fast(zb[i]);
    d   += ua * ub;
    na2 += ua * ua;
    nb2 += ub * ub;
  }
  d   += __shfl_xor(d, 1);   d   += __shfl_xor(d, 2);
  na2 += __shfl_xor(na2, 1); na2 += __shfl_xor(na2, 2);
  nb2 += __shfl_xor(nb2, 1); nb2 += __shfl_xor(nb2, 2);

  if (q == 0) {
    float den = fmaxf(sqrtf(na2), 1e-8f) * fmaxf(sqrtf(nb2), 1e-8f);
    float ov  = d / den;
    float fid = ov * ov;
    out[blockIdx.x * 256 + p] = fminf(fid, 1.0f);
  }
}

extern "C" void kernel_launch(void* const* d_in, const int* in_sizes, int n_in,
                              void* d_out, int out_size, void* d_ws, size_t ws_size,
                              hipStream_t stream) {
  const float* img_a = (const float*)d_in[0];
  const float* img_b = (const float*)d_in[1];
  const float* W1    = (const float*)d_in[2];
  const float* b1    = (const float*)d_in[3];
  const float* W2    = (const float*)d_in[4];
  const float* b2    = (const float*)d_in[5];
  // d_in[6] = theta: unused — the circuit is unitary, fidelity is invariant.

  unsigned short* w1s = (unsigned short*)d_ws;
  float* w2t = (float*)((char*)d_ws + W1S_BYTES);

  prep_kernel<<<(W1S_ELEMS + 255) / 256, 256, 0, stream>>>(W1, W2, w1s, w2t);

  const int n_pairs = out_size;              // 65536
  qcm_kernel<<<n_pairs / 256, 1024, 0, stream>>>(img_a, img_b, b1, b2, w1s, w2t,
                                                 (float*)d_out);
}